// Round 6
// baseline (204.453 us; speedup 1.0000x reference)
//
#include <hip/hip_runtime.h>
#include <hip/hip_bf16.h>

// Causal linear attention, chunked. B=4 H=16 T=2048 D=64. C=128, NC=16.
// Round 6: latency-chain collapse. Three dispatches:
//  1) state_kernel: S_c^T = (K_c^T V_c)^T bf16 -> ws   (single barrier,
//     all global loads issued up front)
//  2) scan_kernel:  cum[c] = sum_{cc<=c} S_cc           (all 15 loads up front)
//  3) attn_kernel:  O = Q_c @ cum[c-1] + tril(Q_c K_c^T) @ V_c
//     - K score B-frags loaded DIRECT from global (contiguous 32 B/lane),
//       no K staging in LDS at all
//     - V both subtiles staged under ONE __syncthreads
//     - cum B-frags direct from global (transposed bf16 layout)

#define T_   2048
#define D_   64
#define CCH  128
#define NCH  16
#define LW   72   // bf16 row stride 144 B (16B aligned)

typedef __bf16 bf16x8 __attribute__((ext_vector_type(8)));
typedef __bf16 bf16x4 __attribute__((ext_vector_type(4)));
typedef float  f32x4  __attribute__((ext_vector_type(4)));

// MFMA 16x16x32 bf16 fragment layouts (HW-verified, rounds 1-5 passing):
//   A: A[m = lane&15][k = (lane>>4)*8 + j]
//   B: B[k = (lane>>4)*8 + j][n = lane&15]
//   C/D: row = (lane>>4)*4 + reg, col = lane&15

__device__ inline bf16x8 pack8(float4 a, float4 b) {
  bf16x8 r;
  r[0] = (__bf16)a.x; r[1] = (__bf16)a.y; r[2] = (__bf16)a.z; r[3] = (__bf16)a.w;
  r[4] = (__bf16)b.x; r[5] = (__bf16)b.y; r[6] = (__bf16)b.z; r[7] = (__bf16)b.w;
  return r;
}

// ------------------------- kernel 1: chunk states -------------------------
__global__ __launch_bounds__(256, 4) void state_kernel(
    const float* __restrict__ k, const float* __restrict__ v,
    __bf16* __restrict__ stws) {
  __shared__ __align__(16) __bf16 KT[2][64][LW];  // [j][d][s]
  __shared__ __align__(16) __bf16 VT[2][64][LW];  // [j][d][s]

  const int tid  = threadIdx.x;
  const int lane = tid & 63;
  const int w    = tid >> 6;
  const int quad = lane >> 4;
  const int l15  = lane & 15;
  const int bh   = (int)blockIdx.x >> 4;
  const int c    = (int)blockIdx.x & (NCH - 1);
  if (c == NCH - 1) return;  // last chunk's state never consumed
  const long base = ((long)bh * T_ + (long)c * CCH) * D_;
  const int d0   = w * 16;

  // issue ALL global loads up front (16 independent dwordx4 per lane)
  float4 kx[2][4], vx[2][4];
#pragma unroll
  for (int j = 0; j < 2; ++j) {
    const float* krow = k + base + (long)(j * 64 + lane) * D_ + d0;
    const float* vrow = v + base + (long)(j * 64 + lane) * D_ + d0;
#pragma unroll
    for (int x = 0; x < 4; ++x) {
      kx[j][x] = *(const float4*)(krow + x * 4);
      vx[j][x] = *(const float4*)(vrow + x * 4);
    }
  }
  // stage transposed; bank = (d*36 + lane/2)%32 -> conflict-free
#pragma unroll
  for (int j = 0; j < 2; ++j)
#pragma unroll
    for (int x = 0; x < 4; ++x) {
      int dd = d0 + x * 4;
      KT[j][dd + 0][lane] = (__bf16)kx[j][x].x;
      KT[j][dd + 1][lane] = (__bf16)kx[j][x].y;
      KT[j][dd + 2][lane] = (__bf16)kx[j][x].z;
      KT[j][dd + 3][lane] = (__bf16)kx[j][x].w;
      VT[j][dd + 0][lane] = (__bf16)vx[j][x].x;
      VT[j][dd + 1][lane] = (__bf16)vx[j][x].y;
      VT[j][dd + 2][lane] = (__bf16)vx[j][x].z;
      VT[j][dd + 3][lane] = (__bf16)vx[j][x].w;
    }
  __syncthreads();  // the ONLY barrier

  const f32x4 vzero = {0.f, 0.f, 0.f, 0.f};
  f32x4 st[4];
#pragma unroll
  for (int n = 0; n < 4; ++n) st[n] = vzero;
#pragma unroll
  for (int j = 0; j < 2; ++j) {
    bf16x8 ka0 = *(const bf16x8*)&KT[j][d0 + l15][quad * 8];
    bf16x8 ka1 = *(const bf16x8*)&KT[j][d0 + l15][32 + quad * 8];
#pragma unroll
    for (int n = 0; n < 4; ++n) {
      bf16x8 b0 = *(const bf16x8*)&VT[j][n * 16 + l15][quad * 8];
      bf16x8 b1 = *(const bf16x8*)&VT[j][n * 16 + l15][32 + quad * 8];
      st[n] = __builtin_amdgcn_mfma_f32_16x16x32_bf16(ka0, b0, st[n], 0, 0, 0);
      st[n] = __builtin_amdgcn_mfma_f32_16x16x32_bf16(ka1, b1, st[n], 0, 0, 0);
    }
  }
  // write TRANSPOSED bf16: stT[d2 = n*16+l15][d1 = d0+quad*4+rr], packed x4
  __bf16* wsp = stws + ((long)blockIdx.x << 12);
#pragma unroll
  for (int n = 0; n < 4; ++n) {
    bf16x4 pk;
    pk[0] = (__bf16)st[n][0]; pk[1] = (__bf16)st[n][1];
    pk[2] = (__bf16)st[n][2]; pk[3] = (__bf16)st[n][3];
    *(bf16x4*)&wsp[(n * 16 + l15) * 64 + d0 + quad * 4] = pk;
  }
}

// ------------------------- kernel 2: cumulative scan ----------------------
// All 15 chunk-slices loaded up front (one burst), then accumulate+store.
__global__ __launch_bounds__(64) void scan_kernel(
    const __bf16* __restrict__ st, __bf16* __restrict__ cum) {
  const int t  = threadIdx.x;
  const int bh = (int)blockIdx.x >> 3;
  const int sl = (int)blockIdx.x & 7;
  const long sbase = ((long)bh * NCH) << 12;
  const int off = sl * 512 + t * 8;  // 16 B per thread

  bf16x8 ch[NCH - 1];
#pragma unroll
  for (int c = 0; c < NCH - 1; ++c)
    ch[c] = *(const bf16x8*)(st + sbase + ((long)c << 12) + off);

  float acc[8];
#pragma unroll
  for (int i = 0; i < 8; ++i) acc[i] = 0.f;
#pragma unroll
  for (int c = 0; c < NCH - 1; ++c) {
#pragma unroll
    for (int i = 0; i < 8; ++i) acc[i] += (float)ch[c][i];
    bf16x8 o;
#pragma unroll
    for (int i = 0; i < 8; ++i) o[i] = (__bf16)acc[i];
    *(bf16x8*)(cum + sbase + ((long)c << 12) + off) = o;
  }
}

// ------------------------- kernel 3: attention ----------------------------
__global__ __launch_bounds__(256, 4) void attn_kernel(
    const float* __restrict__ q, const float* __restrict__ k,
    const float* __restrict__ v, const __bf16* __restrict__ cum,
    float* __restrict__ out) {
  __shared__ __align__(16) __bf16 VT[2][64][LW];     // [j][d][s]
  __shared__ __align__(16) __bf16 Sw[4][2][16][LW];  // per-wave S, dbuf

  const int tid  = threadIdx.x;
  const int lane = tid & 63;
  const int w    = tid >> 6;
  const int quad = lane >> 4;
  const int l15  = lane & 15;
  const int bh   = (int)blockIdx.x >> 4;
  const int c    = (int)blockIdx.x & (NCH - 1);
  const long base = ((long)bh * T_ + (long)c * CCH) * D_;
  const int d0   = w * 16;

  // ---- load burst #1: V (both subtiles), Q frags, cum frags, K0 frags ----
  float4 vx[2][4];
#pragma unroll
  for (int j = 0; j < 2; ++j) {
    const float* vrow = v + base + (long)(j * 64 + lane) * D_ + d0;
#pragma unroll
    for (int x = 0; x < 4; ++x) vx[j][x] = *(const float4*)(vrow + x * 4);
  }
  bf16x8 qf[2][2];
#pragma unroll
  for (int i = 0; i < 2; ++i) {
    const float* qp = q + base + (long)((w + 4 * i) * 16 + l15) * D_ + quad * 8;
#pragma unroll
    for (int ks = 0; ks < 2; ++ks)
      qf[i][ks] = pack8(*(const float4*)(qp + ks * 32),
                        *(const float4*)(qp + ks * 32 + 4));
  }
  bf16x8 kvf[2][4];
  if (c) {
    const __bf16* cp = cum + ((long)(bh * NCH + (c - 1)) << 12);
#pragma unroll
    for (int ks = 0; ks < 2; ++ks)
#pragma unroll
      for (int n = 0; n < 4; ++n)
        kvf[ks][n] =
            *(const bf16x8*)(cp + (n * 16 + l15) * 64 + ks * 32 + quad * 8);
  }
  // K score B-frags, subtile 0, DIRECT from global: B[k=d][n=s] = K[s][d..d+8]
  bf16x8 kf0[2][4];
#pragma unroll
  for (int ks = 0; ks < 2; ++ks)
#pragma unroll
    for (int n = 0; n < 4; ++n) {
      const float* kp = k + base + (long)(n * 16 + l15) * D_ + ks * 32 + quad * 8;
      kf0[ks][n] = pack8(*(const float4*)kp, *(const float4*)(kp + 4));
    }

  // stage V transposed (both subtiles); bank-conflict-free scatter
#pragma unroll
  for (int j = 0; j < 2; ++j)
#pragma unroll
    for (int x = 0; x < 4; ++x) {
      int dd = d0 + x * 4;
      VT[j][dd + 0][lane] = (__bf16)vx[j][x].x;
      VT[j][dd + 1][lane] = (__bf16)vx[j][x].y;
      VT[j][dd + 2][lane] = (__bf16)vx[j][x].z;
      VT[j][dd + 3][lane] = (__bf16)vx[j][x].w;
    }

  const f32x4 vzero = {0.f, 0.f, 0.f, 0.f};
  f32x4 acc[2][4];
#pragma unroll
  for (int i = 0; i < 2; ++i)
#pragma unroll
    for (int n = 0; n < 4; ++n) acc[i][n] = vzero;

  __syncthreads();  // the ONLY barrier: VT visible

  // ---- load burst #2: K subtile-1 frags (in flight during score0/inter)
  bf16x8 kf1[2][4];
#pragma unroll
  for (int ks = 0; ks < 2; ++ks)
#pragma unroll
    for (int n = 0; n < 4; ++n) {
      const float* kp =
          k + base + (long)(64 + n * 16 + l15) * D_ + ks * 32 + quad * 8;
      kf1[ks][n] = pack8(*(const float4*)kp, *(const float4*)(kp + 4));
    }

  // inter: O += Q @ cum[c-1]
  if (c) {
#pragma unroll
    for (int ks = 0; ks < 2; ++ks)
#pragma unroll
      for (int n = 0; n < 4; ++n) {
        acc[0][n] = __builtin_amdgcn_mfma_f32_16x16x32_bf16(qf[0][ks], kvf[ks][n], acc[0][n], 0, 0, 0);
        acc[1][n] = __builtin_amdgcn_mfma_f32_16x16x32_bf16(qf[1][ks], kvf[ks][n], acc[1][n], 0, 0, 0);
      }
  }

  // V B-frags subtile 0
  bf16x8 vb[2][4];
#pragma unroll
  for (int ks = 0; ks < 2; ++ks)
#pragma unroll
    for (int n = 0; n < 4; ++n)
      vb[ks][n] = *(const bf16x8*)&VT[0][n * 16 + l15][ks * 32 + quad * 8];

  // score0: i=0 (diag) and i=1 (full) vs keys 0..63 — from kf0, no LDS
  f32x4 sA[4], sB[4];
#pragma unroll
  for (int n = 0; n < 4; ++n) { sA[n] = vzero; sB[n] = vzero; }
#pragma unroll
  for (int ks = 0; ks < 2; ++ks)
#pragma unroll
    for (int n = 0; n < 4; ++n) {
      sA[n] = __builtin_amdgcn_mfma_f32_16x16x32_bf16(qf[0][ks], kf0[ks][n], sA[n], 0, 0, 0);
      sB[n] = __builtin_amdgcn_mfma_f32_16x16x32_bf16(qf[1][ks], kf0[ks][n], sB[n], 0, 0, 0);
    }

  __bf16* sw0 = &Sw[w][0][0][0];
  __bf16* sw1 = &Sw[w][1][0][0];
#pragma unroll
  for (int n = 0; n < 4; ++n)
#pragma unroll
    for (int rr = 0; rr < 4; ++rr) {
      float val = sA[n][rr];
      if (n * 16 + l15 > 16 * w + quad * 4 + rr) val = 0.f;
      sw0[(quad * 4 + rr) * LW + n * 16 + l15] = (__bf16)val;
      sw1[(quad * 4 + rr) * LW + n * 16 + l15] = (__bf16)sB[n][rr];
    }
  {
    bf16x8 a0 = *(const bf16x8*)&sw0[l15 * LW + quad * 8];
    bf16x8 a1 = *(const bf16x8*)&sw0[l15 * LW + 32 + quad * 8];
    bf16x8 b0 = *(const bf16x8*)&sw1[l15 * LW + quad * 8];
    bf16x8 b1 = *(const bf16x8*)&sw1[l15 * LW + 32 + quad * 8];
#pragma unroll
    for (int n = 0; n < 4; ++n) {
      acc[0][n] = __builtin_amdgcn_mfma_f32_16x16x32_bf16(a0, vb[0][n], acc[0][n], 0, 0, 0);
      acc[0][n] = __builtin_amdgcn_mfma_f32_16x16x32_bf16(a1, vb[1][n], acc[0][n], 0, 0, 0);
      acc[1][n] = __builtin_amdgcn_mfma_f32_16x16x32_bf16(b0, vb[0][n], acc[1][n], 0, 0, 0);
      acc[1][n] = __builtin_amdgcn_mfma_f32_16x16x32_bf16(b1, vb[1][n], acc[1][n], 0, 0, 0);
    }
  }

  // subtile 1: i=1 diagonal (keys 64..127)
#pragma unroll
  for (int ks = 0; ks < 2; ++ks)
#pragma unroll
    for (int n = 0; n < 4; ++n)
      vb[ks][n] = *(const bf16x8*)&VT[1][n * 16 + l15][ks * 32 + quad * 8];

  f32x4 sC[4];
#pragma unroll
  for (int n = 0; n < 4; ++n) sC[n] = vzero;
#pragma unroll
  for (int ks = 0; ks < 2; ++ks)
#pragma unroll
    for (int n = 0; n < 4; ++n)
      sC[n] = __builtin_amdgcn_mfma_f32_16x16x32_bf16(qf[1][ks], kf1[ks][n], sC[n], 0, 0, 0);
#pragma unroll
  for (int n = 0; n < 4; ++n)
#pragma unroll
    for (int rr = 0; rr < 4; ++rr) {
      float val = sC[n][rr];
      if (n * 16 + l15 > 16 * w + quad * 4 + rr) val = 0.f;
      sw0[(quad * 4 + rr) * LW + n * 16 + l15] = (__bf16)val;
    }
  {
    bf16x8 a0 = *(const bf16x8*)&sw0[l15 * LW + quad * 8];
    bf16x8 a1 = *(const bf16x8*)&sw0[l15 * LW + 32 + quad * 8];
#pragma unroll
    for (int n = 0; n < 4; ++n) {
      acc[1][n] = __builtin_amdgcn_mfma_f32_16x16x32_bf16(a0, vb[0][n], acc[1][n], 0, 0, 0);
      acc[1][n] = __builtin_amdgcn_mfma_f32_16x16x32_bf16(a1, vb[1][n], acc[1][n], 0, 0, 0);
    }
  }

  // epilogue
  float* op = out + base;
#pragma unroll
  for (int i = 0; i < 2; ++i) {
    int row = (w + 4 * i) * 16 + quad * 4;
#pragma unroll
    for (int n = 0; n < 4; ++n)
#pragma unroll
      for (int rr = 0; rr < 4; ++rr)
        op[(long)(row + rr) * D_ + n * 16 + l15] = acc[i][n][rr];
  }
}

extern "C" void kernel_launch(void* const* d_in, const int* in_sizes, int n_in,
                              void* d_out, int out_size, void* d_ws, size_t ws_size,
                              hipStream_t stream) {
  const float* q = (const float*)d_in[0];
  const float* k = (const float*)d_in[1];
  const float* v = (const float*)d_in[2];
  float* out = (float*)d_out;
  __bf16* stws = (__bf16*)d_ws;                    // per-chunk states, 8 MiB
  __bf16* cumw = stws + ((long)64 * NCH << 12);    // cumulative states, 8 MiB

  hipLaunchKernelGGL(state_kernel, dim3(64 * NCH), dim3(256), 0, stream,
                     k, v, stws);
  hipLaunchKernelGGL(scan_kernel, dim3(64 * 8), dim3(64), 0, stream,
                     stws, cumw);
  hipLaunchKernelGGL(attn_kernel, dim3(64 * NCH), dim3(256), 0, stream,
                     q, k, v, cumw, out);
}